// Round 2
// baseline (6735.237 us; speedup 1.0000x reference)
//
#include <hip/hip_runtime.h>

#define HH 128
#define WW 128
#define HWP (HH*WW)
#define NC 64
#define NB 2
#define NN 5
#define OFFC 144

// out[b, center=2] = x_center
__global__ __launch_bounds__(256) void copy_center_k(const float* __restrict__ xc,
                                                     float* __restrict__ out) {
    int idx = blockIdx.x * 256 + threadIdx.x;
    const int total = NB * 3 * HWP;
    if (idx >= total) return;
    int b = idx / (3 * HWP);
    int r = idx - b * 3 * HWP;
    out[(size_t)((b * NN + 2) * 3) * HWP + r] = xc[idx];
}

// Direct 3x3 SAME conv, NCHW. 16x16 spatial tile per block (256 threads, 1 px/thread).
// NCO=16 per block (z-split) so acc[] fits registers at 8 waves/SIMD — R1 showed
// NCO=48/64 spilled (VGPR_Count 44/36 < acc size -> scratch loop).
// LDS pitch 48 (== 16 mod 32): 4-rows-per-wave reads land exactly 2 lanes/bank (free).
// MODE 0: in = feature buffer (jl-strided). MODE 1: concat(ref, supp) from pf.
// MODE 2: out = d_out at [b, frame, co, :, :] (rec conv).
template<int CIN, int NCO, int MODE>
__global__ __launch_bounds__(256) void conv3x3_k(
    const float* __restrict__ in, const float* __restrict__ pf,
    const float* __restrict__ w, const float* __restrict__ bias,
    float* __restrict__ out, int job0)
{
    constexpr int CB = 8;                 // channels staged per barrier round
    constexpr int PITCH = 48;             // 18 used, pad to 48 (==16 mod 32)
    constexpr int CH = 18 * PITCH;        // floats per channel in LDS
    const int jl = blockIdx.y;
    const int jg = job0 + jl;
    const int b = jg & 1, fi = jg >> 1;
    const int frame = fi + (fi >= 2 ? 1 : 0);   // center = 2
    const int co0 = blockIdx.z * NCO;
    const int Ct  = gridDim.z * NCO;      // total Cout of this conv
    const int tile = blockIdx.x;          // 8x8 tiles of 16x16
    const int ty0 = (tile >> 3) << 4, tx0 = (tile & 7) << 4;
    const int tid = threadIdx.x;
    const int tx = tid & 15, ty = tid >> 4;

    const float* srcA;
    const float* srcB = nullptr;
    if (MODE == 1) {
        srcA = pf + (size_t)((b * NN + 2) * NC) * HWP;       // ref
        srcB = pf + (size_t)((b * NN + frame) * NC) * HWP;   // supp
    } else {
        srcA = in + (size_t)jl * CIN * HWP;
    }

    __shared__ float lds[CB * CH];
    float acc[NCO];
#pragma unroll
    for (int o = 0; o < NCO; ++o) acc[o] = bias[co0 + o];

    for (int cb = 0; cb < CIN; cb += CB) {
        __syncthreads();
        // stage CB channels of the 18x18 halo tile
        for (int e = tid; e < CB * 324; e += 256) {
            int c = e / 324;
            int r = e - c * 324;
            int iy = r / 18, ix = r - iy * 18;
            int gy = ty0 - 1 + iy, gx = tx0 - 1 + ix;
            int ci = cb + c;
            const float* s;
            if (MODE == 1)
                s = (ci < NC) ? (srcA + (size_t)ci * HWP) : (srcB + (size_t)(ci - NC) * HWP);
            else
                s = srcA + (size_t)ci * HWP;
            float v = 0.f;
            if (gy >= 0 && gy < HH && gx >= 0 && gx < WW) v = s[gy * WW + gx];
            lds[c * CH + iy * PITCH + ix] = v;
        }
        __syncthreads();
#pragma unroll
        for (int c = 0; c < CB; ++c) {
            float t[9];
#pragma unroll
            for (int dy = 0; dy < 3; ++dy)
#pragma unroll
                for (int dx = 0; dx < 3; ++dx)
                    t[dy * 3 + dx] = lds[c * CH + (ty + dy) * PITCH + (tx + dx)];
            int ci = cb + c;
#pragma unroll
            for (int o = 0; o < NCO; ++o) {
                const float* wo = w + ((size_t)(co0 + o) * CIN + ci) * 9;
#pragma unroll
                for (int kk = 0; kk < 9; ++kk)
                    acc[o] = fmaf(wo[kk], t[kk], acc[o]);
            }
        }
    }
    const int oy = ty0 + ty, ox = tx0 + tx;
#pragma unroll
    for (int o = 0; o < NCO; ++o) {
        float v = acc[o];
        if (MODE == 2)
            out[((size_t)(b * NN + frame) * 3 + (co0 + o)) * HWP + oy * WW + ox] = v;
        else
            out[((size_t)jl * Ct + co0 + o) * HWP + oy * WW + ox] = v;
    }
}

// Deformable conv (v1, DG=8, Cg=8, 3x3). Block = 256 thr = 8x8 px tile x 4 waves.
// Wave q computes out channels [16q, 16q+16). Per group g:
//  phase A: 576 (px,kk) tasks -> bilinear samples for 8 cg into LDS (pitch 73, 2-way = free).
//  phase B: 72 LDS reads + 1152 fma per thread, weights via uniform s_load.
__global__ __launch_bounds__(256) void deform_k(
    const float* __restrict__ in, const float* __restrict__ off,
    const float* __restrict__ w, const float* __restrict__ bias,
    float* __restrict__ out, int job0, int supp_mode, const float* __restrict__ pf)
{
    const int jl = blockIdx.y;
    const int jg = job0 + jl;
    const int b = jg & 1, fi = jg >> 1;
    const int frame = fi + (fi >= 2 ? 1 : 0);
    const int tile = blockIdx.x;          // 16x16 tiles of 8x8
    const int ty0 = (tile >> 4) << 3, tx0 = (tile & 15) << 3;
    const int tid = threadIdx.x;
    const int p = tid & 63;
    const int q = __builtin_amdgcn_readfirstlane(tid >> 6);  // wave-uniform co-group

    const float* ibase = supp_mode ? (pf + (size_t)((b * NN + frame) * NC) * HWP)
                                   : (in + (size_t)jl * NC * HWP);
    const float* obase = off + (size_t)jl * OFFC * HWP;

    __shared__ float samp[64 * 73];
    float acc[16];
#pragma unroll
    for (int o = 0; o < 16; ++o) acc[o] = bias[q * 16 + o];

    for (int g = 0; g < 8; ++g) {
        __syncthreads();
        // ---- phase A: bilinear sampling into LDS ----
        for (int tk = tid; tk < 576; tk += 256) {
            int kk = tk >> 6;             // 0..8
            int pp = tk & 63;
            int yy = ty0 + (pp >> 3), xx = tx0 + (pp & 7);
            int ch = (g * 9 + kk) * 2;    // offset channel layout: (g, kk, {y,x})
            float oyv = obase[(size_t)ch * HWP + yy * WW + xx];
            float oxv = obase[(size_t)(ch + 1) * HWP + yy * WW + xx];
            float py = (float)(yy + (kk / 3) - 1) + oyv;
            float px = (float)(xx + (kk % 3) - 1) + oxv;
            float fy = floorf(py), fx = floorf(px);
            float wy = py - fy, wx = px - fx;
            int y0 = (int)fy, x0 = (int)fx;
            int y1 = y0 + 1, x1 = x0 + 1;
            float m00 = (y0 >= 0 && y0 < HH && x0 >= 0 && x0 < WW) ? 1.f : 0.f;
            float m01 = (y0 >= 0 && y0 < HH && x1 >= 0 && x1 < WW) ? 1.f : 0.f;
            float m10 = (y1 >= 0 && y1 < HH && x0 >= 0 && x0 < WW) ? 1.f : 0.f;
            float m11 = (y1 >= 0 && y1 < HH && x1 >= 0 && x1 < WW) ? 1.f : 0.f;
            float w00 = (1.f - wy) * (1.f - wx) * m00;
            float w01 = (1.f - wy) * wx * m01;
            float w10 = wy * (1.f - wx) * m10;
            float w11 = wy * wx * m11;
            int cy0 = min(max(y0, 0), HH - 1), cy1 = min(max(y1, 0), HH - 1);
            int cx0 = min(max(x0, 0), WW - 1), cx1 = min(max(x1, 0), WW - 1);
            int a00 = cy0 * WW + cx0, a01 = cy0 * WW + cx1;
            int a10 = cy1 * WW + cx0, a11 = cy1 * WW + cx1;
            const float* ib = ibase + (size_t)(g * 8) * HWP;
#pragma unroll
            for (int cg = 0; cg < 8; ++cg) {
                const float* ip = ib + (size_t)cg * HWP;
                float s = ip[a00] * w00;
                s = fmaf(ip[a01], w01, s);
                s = fmaf(ip[a10], w10, s);
                s = fmaf(ip[a11], w11, s);
                samp[pp * 73 + cg * 9 + kk] = s;
            }
        }
        __syncthreads();
        // ---- phase B: contraction (16 couts per wave) ----
#pragma unroll
        for (int cg = 0; cg < 8; ++cg) {
            int cin = g * 8 + cg;
            const float* wrow = w + ((size_t)(q * 16) * NC + cin) * 9;
#pragma unroll
            for (int kk = 0; kk < 9; ++kk) {
                float s = samp[p * 73 + cg * 9 + kk];
#pragma unroll
                for (int o = 0; o < 16; ++o)
                    acc[o] = fmaf(wrow[(size_t)o * NC * 9 + kk], s, acc[o]);
            }
        }
    }
    const int oy = ty0 + (p >> 3), ox = tx0 + (p & 7);
#pragma unroll
    for (int o = 0; o < 16; ++o) {
        int co = q * 16 + o;
        out[((size_t)jl * NC + co) * HWP + oy * WW + ox] = acc[o];
    }
}

extern "C" void kernel_launch(void* const* d_in, const int* in_sizes, int n_in,
                              void* d_out, int out_size, void* d_ws, size_t ws_size,
                              hipStream_t stream)
{
    const float* pf    = (const float*)d_in[0];
    const float* xc    = (const float*)d_in[1];
    const float* cr_w  = (const float*)d_in[2];
    const float* cr_b  = (const float*)d_in[3];
    const float* ow[4] = {(const float*)d_in[4],  (const float*)d_in[8],
                          (const float*)d_in[12], (const float*)d_in[16]};
    const float* ob[4] = {(const float*)d_in[5],  (const float*)d_in[9],
                          (const float*)d_in[13], (const float*)d_in[17]};
    const float* dw[4] = {(const float*)d_in[6],  (const float*)d_in[10],
                          (const float*)d_in[14], (const float*)d_in[18]};
    const float* db[4] = {(const float*)d_in[7],  (const float*)d_in[11],
                          (const float*)d_in[15], (const float*)d_in[19]};
    const float* rec_w = (const float*)d_in[20];
    const float* rec_b = (const float*)d_in[21];
    float* out = (float*)d_out;

    // Workspace: A (64ch) + B (64ch) + O (144ch) per job; chunk jobs if ws is small.
    const size_t per_job = (size_t)(NC + NC + OFFC) * HWP * sizeof(float);  // ~17.8 MB
    int JC = 8;
    while (JC > 1 && per_job * (size_t)JC > ws_size) JC >>= 1;
    float* A  = (float*)d_ws;
    float* Bb = A  + (size_t)JC * NC * HWP;
    float* O  = Bb + (size_t)JC * NC * HWP;

    copy_center_k<<<dim3((NB * 3 * HWP + 255) / 256), 256, 0, stream>>>(xc, out);

    for (int job0 = 0; job0 < 8; job0 += JC) {
        dim3 blk(256);
        // fea1 = cr_conv(concat(ref, supp))
        conv3x3_k<128, 16, 1><<<dim3(64, JC, 4), blk, 0, stream>>>(nullptr, pf, cr_w, cr_b, A, job0);
        // off1(fea1); fea2 = deform(fea1)
        conv3x3_k<64, 16, 0><<<dim3(64, JC, 9), blk, 0, stream>>>(A, nullptr, ow[0], ob[0], O, job0);
        deform_k<<<dim3(256, JC), blk, 0, stream>>>(A, O, dw[0], db[0], Bb, job0, 0, pf);
        // off2(fea2); fea3 = deform(fea2)
        conv3x3_k<64, 16, 0><<<dim3(64, JC, 9), blk, 0, stream>>>(Bb, nullptr, ow[1], ob[1], O, job0);
        deform_k<<<dim3(256, JC), blk, 0, stream>>>(Bb, O, dw[1], db[1], A, job0, 0, pf);
        // off3(fea3); fea4 = deform(supp)
        conv3x3_k<64, 16, 0><<<dim3(64, JC, 9), blk, 0, stream>>>(A, nullptr, ow[2], ob[2], O, job0);
        deform_k<<<dim3(256, JC), blk, 0, stream>>>(nullptr, O, dw[2], db[2], Bb, job0, 1, pf);
        // off4(fea4); aligned = deform(fea4)
        conv3x3_k<64, 16, 0><<<dim3(64, JC, 9), blk, 0, stream>>>(Bb, nullptr, ow[3], ob[3], O, job0);
        deform_k<<<dim3(256, JC), blk, 0, stream>>>(Bb, O, dw[3], db[3], A, job0, 0, pf);
        // out[b, frame] = rec_conv(aligned)
        conv3x3_k<64, 3, 2><<<dim3(64, JC, 1), blk, 0, stream>>>(A, nullptr, rec_w, rec_b, out, job0);
    }
}

// Round 3
// 4301.956 us; speedup vs baseline: 1.5656x; 1.5656x over previous
//
#include <hip/hip_runtime.h>

#define HH 128
#define WW 128
#define HWP (HH*WW)
#define NC 64
#define NB 2
#define NN 5
#define OFFC 144

// out[b, center=2] = x_center
__global__ __launch_bounds__(256) void copy_center_k(const float* __restrict__ xc,
                                                     float* __restrict__ out) {
    int idx = blockIdx.x * 256 + threadIdx.x;
    const int total = NB * 3 * HWP;
    if (idx >= total) return;
    int b = idx / (3 * HWP);
    int r = idx - b * 3 * HWP;
    out[(size_t)((b * NN + 2) * 3) * HWP + r] = xc[idx];
}

// 3x3 SAME conv, deform-style structure: block = 8x8 px tile x 4 waves.
// Wave q computes couts [co0b + q*NCOW, +NCOW). One 10x10 halo staging (pitch 12,
// exact 2-way banking = free) feeds 4*NCOW couts -> ~7x more MACs per staged float
// than the R2 z-split layout. Weights via wave-uniform s_loads (deform-proven).
// MODE 0: in = feature buffer (jl-strided). MODE 1: concat(ref, supp) from pf.
template<int CIN, int NCOW, int MODE>
__global__ __launch_bounds__(256) void conv3x3_w_k(
    const float* __restrict__ in, const float* __restrict__ pf,
    const float* __restrict__ w, const float* __restrict__ bias,
    float* __restrict__ out, int job0)
{
    constexpr int CB = 16;                // channels staged per barrier round
    constexpr int PITCH = 12;             // 10 used; (py*12+px)%32 -> exact 2-way
    constexpr int CH = 10 * PITCH;        // floats per channel in LDS
    const int jl = blockIdx.y;
    const int jg = job0 + jl;
    const int b = jg & 1, fi = jg >> 1;
    const int frame = fi + (fi >= 2 ? 1 : 0);   // center = 2
    const int NCOB = 4 * NCOW;
    const int co0b = blockIdx.z * NCOB;
    const int Ct = gridDim.z * NCOB;
    const int tile = blockIdx.x;          // 16x16 tiles of 8x8
    const int ty0 = (tile >> 4) << 3, tx0 = (tile & 15) << 3;
    const int tid = threadIdx.x;
    const int p = tid & 63;
    const int q = __builtin_amdgcn_readfirstlane(tid >> 6);  // wave-uniform co-group
    const int px = p & 7, py = p >> 3;
    const int co0 = co0b + q * NCOW;

    const float* srcA;
    const float* srcB = nullptr;
    if (MODE == 1) {
        srcA = pf + (size_t)((b * NN + 2) * NC) * HWP;       // ref
        srcB = pf + (size_t)((b * NN + frame) * NC) * HWP;   // supp
    } else {
        srcA = in + (size_t)jl * CIN * HWP;
    }

    __shared__ float lds[CB * CH];
    float acc[NCOW];
#pragma unroll
    for (int o = 0; o < NCOW; ++o) acc[o] = bias[co0 + o];

    for (int cb = 0; cb < CIN; cb += CB) {
        __syncthreads();
        // stage CB channels of the 10x10 halo tile
        for (int e = tid; e < CB * 100; e += 256) {
            int c = e / 100;
            int r = e - c * 100;
            int iy = r / 10, ix = r - iy * 10;
            int gy = ty0 - 1 + iy, gx = tx0 - 1 + ix;
            int ci = cb + c;
            const float* s;
            if (MODE == 1)
                s = (ci < NC) ? (srcA + (size_t)ci * HWP) : (srcB + (size_t)(ci - NC) * HWP);
            else
                s = srcA + (size_t)ci * HWP;
            float v = 0.f;
            if (gy >= 0 && gy < HH && gx >= 0 && gx < WW) v = s[gy * WW + gx];
            lds[c * CH + iy * PITCH + ix] = v;
        }
        __syncthreads();
        for (int c = 0; c < CB; ++c) {
            float t[9];
#pragma unroll
            for (int dy = 0; dy < 3; ++dy)
#pragma unroll
                for (int dx = 0; dx < 3; ++dx)
                    t[dy * 3 + dx] = lds[c * CH + (py + dy) * PITCH + (px + dx)];
            const float* wb = w + ((size_t)co0 * CIN + (cb + c)) * 9;
#pragma unroll
            for (int o = 0; o < NCOW; ++o) {
#pragma unroll
                for (int kk = 0; kk < 9; ++kk)
                    acc[o] = fmaf(wb[(size_t)o * CIN * 9 + kk], t[kk], acc[o]);
            }
        }
    }
    const int oy = ty0 + py, ox = tx0 + px;
#pragma unroll
    for (int o = 0; o < NCOW; ++o)
        out[((size_t)jl * Ct + (co0 + o)) * HWP + oy * WW + ox] = acc[o];
}

// rec conv (64 -> 3): tiny; 16x16 tile, 1 px/thread, acc[3]. Writes d_out.
__global__ __launch_bounds__(256) void conv3x3_rec_k(
    const float* __restrict__ in, const float* __restrict__ w,
    const float* __restrict__ bias, float* __restrict__ out, int job0)
{
    constexpr int CB = 8;
    constexpr int PITCH = 48;
    constexpr int CH = 18 * PITCH;
    const int jl = blockIdx.y;
    const int jg = job0 + jl;
    const int b = jg & 1, fi = jg >> 1;
    const int frame = fi + (fi >= 2 ? 1 : 0);
    const int tile = blockIdx.x;
    const int ty0 = (tile >> 3) << 4, tx0 = (tile & 7) << 4;
    const int tid = threadIdx.x;
    const int tx = tid & 15, ty = tid >> 4;
    const float* srcA = in + (size_t)jl * NC * HWP;

    __shared__ float lds[CB * CH];
    float acc[3] = {bias[0], bias[1], bias[2]};

    for (int cb = 0; cb < NC; cb += CB) {
        __syncthreads();
        for (int e = tid; e < CB * 324; e += 256) {
            int c = e / 324;
            int r = e - c * 324;
            int iy = r / 18, ix = r - iy * 18;
            int gy = ty0 - 1 + iy, gx = tx0 - 1 + ix;
            const float* s = srcA + (size_t)(cb + c) * HWP;
            float v = 0.f;
            if (gy >= 0 && gy < HH && gx >= 0 && gx < WW) v = s[gy * WW + gx];
            lds[c * CH + iy * PITCH + ix] = v;
        }
        __syncthreads();
#pragma unroll
        for (int c = 0; c < CB; ++c) {
            float t[9];
#pragma unroll
            for (int dy = 0; dy < 3; ++dy)
#pragma unroll
                for (int dx = 0; dx < 3; ++dx)
                    t[dy * 3 + dx] = lds[c * CH + (ty + dy) * PITCH + (tx + dx)];
            int ci = cb + c;
#pragma unroll
            for (int o = 0; o < 3; ++o) {
                const float* wo = w + ((size_t)o * NC + ci) * 9;
#pragma unroll
                for (int kk = 0; kk < 9; ++kk)
                    acc[o] = fmaf(wo[kk], t[kk], acc[o]);
            }
        }
    }
    const int oy = ty0 + ty, ox = tx0 + tx;
#pragma unroll
    for (int o = 0; o < 3; ++o)
        out[((size_t)(b * NN + frame) * 3 + o) * HWP + oy * WW + ox] = acc[o];
}

// Deformable conv (v1, DG=8, Cg=8, 3x3). Block = 256 thr = 8x8 px tile x 4 waves.
__global__ __launch_bounds__(256) void deform_k(
    const float* __restrict__ in, const float* __restrict__ off,
    const float* __restrict__ w, const float* __restrict__ bias,
    float* __restrict__ out, int job0, int supp_mode, const float* __restrict__ pf)
{
    const int jl = blockIdx.y;
    const int jg = job0 + jl;
    const int b = jg & 1, fi = jg >> 1;
    const int frame = fi + (fi >= 2 ? 1 : 0);
    const int tile = blockIdx.x;          // 16x16 tiles of 8x8
    const int ty0 = (tile >> 4) << 3, tx0 = (tile & 15) << 3;
    const int tid = threadIdx.x;
    const int p = tid & 63;
    const int q = __builtin_amdgcn_readfirstlane(tid >> 6);  // wave-uniform co-group

    const float* ibase = supp_mode ? (pf + (size_t)((b * NN + frame) * NC) * HWP)
                                   : (in + (size_t)jl * NC * HWP);
    const float* obase = off + (size_t)jl * OFFC * HWP;

    __shared__ float samp[64 * 73];
    float acc[16];
#pragma unroll
    for (int o = 0; o < 16; ++o) acc[o] = bias[q * 16 + o];

    for (int g = 0; g < 8; ++g) {
        __syncthreads();
        // ---- phase A: bilinear sampling into LDS ----
        for (int tk = tid; tk < 576; tk += 256) {
            int kk = tk >> 6;             // 0..8
            int pp = tk & 63;
            int yy = ty0 + (pp >> 3), xx = tx0 + (pp & 7);
            int ch = (g * 9 + kk) * 2;    // offset channel layout: (g, kk, {y,x})
            float oyv = obase[(size_t)ch * HWP + yy * WW + xx];
            float oxv = obase[(size_t)(ch + 1) * HWP + yy * WW + xx];
            float pyf = (float)(yy + (kk / 3) - 1) + oyv;
            float pxf = (float)(xx + (kk % 3) - 1) + oxv;
            float fy = floorf(pyf), fx = floorf(pxf);
            float wy = pyf - fy, wx = pxf - fx;
            int y0 = (int)fy, x0 = (int)fx;
            int y1 = y0 + 1, x1 = x0 + 1;
            float m00 = (y0 >= 0 && y0 < HH && x0 >= 0 && x0 < WW) ? 1.f : 0.f;
            float m01 = (y0 >= 0 && y0 < HH && x1 >= 0 && x1 < WW) ? 1.f : 0.f;
            float m10 = (y1 >= 0 && y1 < HH && x0 >= 0 && x0 < WW) ? 1.f : 0.f;
            float m11 = (y1 >= 0 && y1 < HH && x1 >= 0 && x1 < WW) ? 1.f : 0.f;
            float w00 = (1.f - wy) * (1.f - wx) * m00;
            float w01 = (1.f - wy) * wx * m01;
            float w10 = wy * (1.f - wx) * m10;
            float w11 = wy * wx * m11;
            int cy0 = min(max(y0, 0), HH - 1), cy1 = min(max(y1, 0), HH - 1);
            int cx0 = min(max(x0, 0), WW - 1), cx1 = min(max(x1, 0), WW - 1);
            int a00 = cy0 * WW + cx0, a01 = cy0 * WW + cx1;
            int a10 = cy1 * WW + cx0, a11 = cy1 * WW + cx1;
            const float* ib = ibase + (size_t)(g * 8) * HWP;
#pragma unroll
            for (int cg = 0; cg < 8; ++cg) {
                const float* ip = ib + (size_t)cg * HWP;
                float s = ip[a00] * w00;
                s = fmaf(ip[a01], w01, s);
                s = fmaf(ip[a10], w10, s);
                s = fmaf(ip[a11], w11, s);
                samp[pp * 73 + cg * 9 + kk] = s;
            }
        }
        __syncthreads();
        // ---- phase B: contraction (16 couts per wave) ----
#pragma unroll
        for (int cg = 0; cg < 8; ++cg) {
            int cin = g * 8 + cg;
            const float* wrow = w + ((size_t)(q * 16) * NC + cin) * 9;
#pragma unroll
            for (int kk = 0; kk < 9; ++kk) {
                float s = samp[p * 73 + cg * 9 + kk];
#pragma unroll
                for (int o = 0; o < 16; ++o)
                    acc[o] = fmaf(wrow[(size_t)o * NC * 9 + kk], s, acc[o]);
            }
        }
    }
    const int oy = ty0 + (p >> 3), ox = tx0 + (p & 7);
#pragma unroll
    for (int o = 0; o < 16; ++o) {
        int co = q * 16 + o;
        out[((size_t)jl * NC + co) * HWP + oy * WW + ox] = acc[o];
    }
}

extern "C" void kernel_launch(void* const* d_in, const int* in_sizes, int n_in,
                              void* d_out, int out_size, void* d_ws, size_t ws_size,
                              hipStream_t stream)
{
    const float* pf    = (const float*)d_in[0];
    const float* xc    = (const float*)d_in[1];
    const float* cr_w  = (const float*)d_in[2];
    const float* cr_b  = (const float*)d_in[3];
    const float* ow[4] = {(const float*)d_in[4],  (const float*)d_in[8],
                          (const float*)d_in[12], (const float*)d_in[16]};
    const float* ob[4] = {(const float*)d_in[5],  (const float*)d_in[9],
                          (const float*)d_in[13], (const float*)d_in[17]};
    const float* dw[4] = {(const float*)d_in[6],  (const float*)d_in[10],
                          (const float*)d_in[14], (const float*)d_in[18]};
    const float* db[4] = {(const float*)d_in[7],  (const float*)d_in[11],
                          (const float*)d_in[15], (const float*)d_in[19]};
    const float* rec_w = (const float*)d_in[20];
    const float* rec_b = (const float*)d_in[21];
    float* out = (float*)d_out;

    // Workspace: A (64ch) + B (64ch) + O (144ch) per job; chunk jobs if ws is small.
    const size_t per_job = (size_t)(NC + NC + OFFC) * HWP * sizeof(float);  // ~17.8 MB
    int JC = 8;
    while (JC > 1 && per_job * (size_t)JC > ws_size) JC >>= 1;
    float* A  = (float*)d_ws;
    float* Bb = A  + (size_t)JC * NC * HWP;
    float* O  = Bb + (size_t)JC * NC * HWP;

    copy_center_k<<<dim3((NB * 3 * HWP + 255) / 256), 256, 0, stream>>>(xc, out);

    for (int job0 = 0; job0 < 8; job0 += JC) {
        dim3 blk(256);
        // fea1 = cr_conv(concat(ref, supp))  : 128 -> 64, 16 co/wave, z=1
        conv3x3_w_k<128, 16, 1><<<dim3(256, JC, 1), blk, 0, stream>>>(nullptr, pf, cr_w, cr_b, A, job0);
        // off1(fea1); fea2 = deform(fea1)    : 64 -> 144, 18 co/wave, z=2
        conv3x3_w_k<64, 18, 0><<<dim3(256, JC, 2), blk, 0, stream>>>(A, nullptr, ow[0], ob[0], O, job0);
        deform_k<<<dim3(256, JC), blk, 0, stream>>>(A, O, dw[0], db[0], Bb, job0, 0, pf);
        // off2(fea2); fea3 = deform(fea2)
        conv3x3_w_k<64, 18, 0><<<dim3(256, JC, 2), blk, 0, stream>>>(Bb, nullptr, ow[1], ob[1], O, job0);
        deform_k<<<dim3(256, JC), blk, 0, stream>>>(Bb, O, dw[1], db[1], A, job0, 0, pf);
        // off3(fea3); fea4 = deform(supp)
        conv3x3_w_k<64, 18, 0><<<dim3(256, JC, 2), blk, 0, stream>>>(A, nullptr, ow[2], ob[2], O, job0);
        deform_k<<<dim3(256, JC), blk, 0, stream>>>(nullptr, O, dw[2], db[2], Bb, job0, 1, pf);
        // off4(fea4); aligned = deform(fea4)
        conv3x3_w_k<64, 18, 0><<<dim3(256, JC, 2), blk, 0, stream>>>(Bb, nullptr, ow[3], ob[3], O, job0);
        deform_k<<<dim3(256, JC), blk, 0, stream>>>(Bb, O, dw[3], db[3], A, job0, 0, pf);
        // out[b, frame] = rec_conv(aligned)  : 64 -> 3
        conv3x3_rec_k<<<dim3(64, JC, 1), blk, 0, stream>>>(A, rec_w, rec_b, out, job0);
    }
}

// Round 8
// 2809.896 us; speedup vs baseline: 2.3970x; 1.5310x over previous
//
#include <hip/hip_runtime.h>

#define HH 128
#define WW 128
#define HWP (HH*WW)
#define NC 64
#define NB 2
#define NN 5
#define OFFC 144
#define NKC 18                    // K-chunks of 32 per 576-K conv pass

typedef __attribute__((ext_vector_type(8))) _Float16 half8;
typedef __attribute__((ext_vector_type(4))) float floatx4;

// out[b, center=2] = x_center
__global__ __launch_bounds__(256) void copy_center_k(const float* __restrict__ xc,
                                                     float* __restrict__ out) {
    int idx = blockIdx.x * 256 + threadIdx.x;
    const int total = NB * 3 * HWP;
    if (idx >= total) return;
    int b = idx / (3 * HWP);
    int r = idx - b * 3 * HWP;
    out[(size_t)((b * NN + 2) * 3) * HWP + r] = xc[idx];
}

// Weight preprocessor, SPLIT-fp16: fp32 w[co][cin_src][9] -> A-frag pairs
// wp[ct][kc][{hi,lo}][lane][8]: element j of lane = w[ct*16+(lane&15)][ci(k)][kk(k)],
// k = kc*32 + (lane>>4)*8 + j, decoded kk = k>>6, ci = k&63 (+ci_off into source).
// hi = fp16(w), lo = fp16(w - hi).
__global__ __launch_bounds__(256) void prew_k(const float* __restrict__ w,
                                              _Float16* __restrict__ wp,
                                              int nct, int ci_off, int cin_src)
{
    int idx = blockIdx.x * 256 + threadIdx.x;   // ((ct*18 + kc)*64 + lane)
    if (idx >= nct * NKC * 64) return;
    int lane = idx & 63;
    int kc = (idx >> 6) % NKC;
    int ct = (idx >> 6) / NKC;
    int m = lane & 15, quad = lane >> 4;
    int co = ct * 16 + m;
    union { half8 v; _Float16 e[8]; } ph, pl;
#pragma unroll
    for (int j = 0; j < 8; ++j) {
        int k = kc * 32 + quad * 8 + j;
        int kk = k >> 6, ci = k & 63;
        float f = w[((size_t)co * cin_src + ci_off + ci) * 9 + kk];
        _Float16 h = (_Float16)f;
        _Float16 l = (_Float16)(f - (float)h);
        ph.e[j] = h; pl.e[j] = l;
    }
    size_t base = (size_t)((ct * NKC + kc) * 2) * 512;   // chunk = 2*64*8 elems
    *(half8*)(wp + base + lane * 8) = ph.v;
    *(half8*)(wp + base + 512 + lane * 8) = pl.v;
}

// SPLIT-fp16 MFMA 3x3 conv: CIN=64 per pass, K=576. Block = 16(x) x 8(y) px tile,
// 4 waves; wave wq -> rows {2wq, 2wq+1}; lane n = x. Full halo (10x18 x 64ci)
// resident as fp16 hi+lo planes [cb(8)][hy][hx][ci8(8)] (PL pad -> 2-way banks, free).
// Per product: acc += Ah*Bh + Ah*Bl + Al*Bh  (drops ~2^-22 lo*lo -> fp32-class).
// Epilogue D-map hardcoded = probe-validated: co = ct*16 + quad*4 + i, x = tx0 + n.
// SRCMODE 0: ws feature buf (jl-strided). 1: pf ref. 2: pf supp. ADD: out += (2nd pass).
template<int NCT, int SRCMODE, int ADD>
__global__ __launch_bounds__(256, 2) void mconv_k(
    const float* __restrict__ src, const float* __restrict__ pf,
    const _Float16* __restrict__ wp, const float* __restrict__ bias,
    float* __restrict__ out, int job0)
{
    constexpr int PL = 1456;              // 10*18*8 = 1440 + 16 pad (fp16 elems)
    const int jl = blockIdx.y, jg = job0 + jl;
    const int b = jg & 1, fi = jg >> 1;
    const int frame = fi + (fi >= 2 ? 1 : 0);
    const int tile = blockIdx.x;          // 128 tiles: 8 in x, 16 in y
    const int ty0 = (tile >> 3) << 3, tx0 = (tile & 7) << 4;
    const int tid = threadIdx.x;
    const int lane = tid & 63;
    const int wq = __builtin_amdgcn_readfirstlane(tid >> 6);
    const int n = lane & 15, quad = lane >> 4;

    const float* s0;
    if (SRCMODE == 0)      s0 = src + (size_t)jl * NC * HWP;
    else if (SRCMODE == 1) s0 = pf + (size_t)((b * NN + 2) * NC) * HWP;
    else                   s0 = pf + (size_t)((b * NN + frame) * NC) * HWP;

    __shared__ _Float16 hh[8 * PL];
    __shared__ _Float16 ll[8 * PL];

    // ---- stage halo (180 px x 64 ci) as fp16 hi/lo ----
    for (int t = tid; t < 360; t += 256) {
        int px = t >> 1, hf = t & 1;      // hf: ci 0-31 / 32-63
        int hy = px / 18, hx = px - hy * 18;
        int gy = ty0 - 1 + hy, gx = tx0 - 1 + hx;
        bool ok = (gy >= 0 && gy < HH && gx >= 0 && gx < WW);
        const float* sp = s0 + ((long)(ok ? gy : 0) * WW + (ok ? gx : 0));
        int lb = px * 8;
#pragma unroll
        for (int c = 0; c < 4; ++c) {
            int cb = hf * 4 + c;
            union { half8 v; _Float16 e[8]; } ph, pl;
#pragma unroll
            for (int j = 0; j < 8; ++j) {
                float f = ok ? sp[(size_t)(cb * 8 + j) * HWP] : 0.f;
                _Float16 h = (_Float16)f;
                ph.e[j] = h;
                pl.e[j] = (_Float16)(f - (float)h);
            }
            *(half8*)&hh[cb * PL + lb] = ph.v;
            *(half8*)&ll[cb * PL + lb] = pl.v;
        }
    }
    __syncthreads();

    // ---- compute ----
    for (int ct = 0; ct < NCT; ++ct) {
        half8 Ah[NKC], Al[NKC];
#pragma unroll
        for (int kc = 0; kc < NKC; ++kc) {
            size_t base = (size_t)((ct * NKC + kc) * 2) * 512;
            Ah[kc] = *(const half8*)(wp + base + lane * 8);
            Al[kc] = *(const half8*)(wp + base + 512 + lane * 8);
        }
#pragma unroll
        for (int r = 0; r < 2; ++r) {
            const int y = wq * 2 + r;
            floatx4 acc = {0.f, 0.f, 0.f, 0.f};
#pragma unroll
            for (int kc = 0; kc < NKC; ++kc) {
                const int kk = kc >> 1;
                const int dy = kk / 3, dx = kk % 3;
                const int cb = ((kc & 1) << 2) + quad;
                const int ix = cb * PL + ((y + dy) * 18 + n + dx) * 8;
                half8 Bh = *(const half8*)&hh[ix];
                half8 Bl = *(const half8*)&ll[ix];
                acc = __builtin_amdgcn_mfma_f32_16x16x32_f16(Ah[kc], Bh, acc, 0, 0, 0);
                acc = __builtin_amdgcn_mfma_f32_16x16x32_f16(Ah[kc], Bl, acc, 0, 0, 0);
                acc = __builtin_amdgcn_mfma_f32_16x16x32_f16(Al[kc], Bh, acc, 0, 0, 0);
            }
            const int oy = ty0 + y, ox = tx0 + n;
#pragma unroll
            for (int i = 0; i < 4; ++i) {
                int co = ct * 16 + quad * 4 + i;
                size_t oi = ((size_t)jl * (NCT * 16) + co) * HWP + (size_t)oy * WW + ox;
                float v = acc[i];
                if (ADD) v += out[oi];
                else     v += bias[co];
                out[oi] = v;
            }
        }
    }
}

// Deformable conv (v1, DG=8, Cg=8, 3x3) — R3-proven fp32 version.
__global__ __launch_bounds__(256) void deform_k(
    const float* __restrict__ in, const float* __restrict__ off,
    const float* __restrict__ w, const float* __restrict__ bias,
    float* __restrict__ out, int job0, int supp_mode, const float* __restrict__ pf)
{
    const int jl = blockIdx.y;
    const int jg = job0 + jl;
    const int b = jg & 1, fi = jg >> 1;
    const int frame = fi + (fi >= 2 ? 1 : 0);
    const int tile = blockIdx.x;          // 16x16 tiles of 8x8
    const int ty0 = (tile >> 4) << 3, tx0 = (tile & 15) << 3;
    const int tid = threadIdx.x;
    const int p = tid & 63;
    const int q = __builtin_amdgcn_readfirstlane(tid >> 6);

    const float* ibase = supp_mode ? (pf + (size_t)((b * NN + frame) * NC) * HWP)
                                   : (in + (size_t)jl * NC * HWP);
    const float* obase = off + (size_t)jl * OFFC * HWP;

    __shared__ float samp[64 * 73];
    float acc[16];
#pragma unroll
    for (int o = 0; o < 16; ++o) acc[o] = bias[q * 16 + o];

    for (int g = 0; g < 8; ++g) {
        __syncthreads();
        for (int tk = tid; tk < 576; tk += 256) {
            int kk = tk >> 6;
            int pp = tk & 63;
            int yy = ty0 + (pp >> 3), xx = tx0 + (pp & 7);
            int ch = (g * 9 + kk) * 2;
            float oyv = obase[(size_t)ch * HWP + yy * WW + xx];
            float oxv = obase[(size_t)(ch + 1) * HWP + yy * WW + xx];
            float pyf = (float)(yy + (kk / 3) - 1) + oyv;
            float pxf = (float)(xx + (kk % 3) - 1) + oxv;
            float fy = floorf(pyf), fx = floorf(pxf);
            float wy = pyf - fy, wx = pxf - fx;
            int y0 = (int)fy, x0 = (int)fx;
            int y1 = y0 + 1, x1 = x0 + 1;
            float m00 = (y0 >= 0 && y0 < HH && x0 >= 0 && x0 < WW) ? 1.f : 0.f;
            float m01 = (y0 >= 0 && y0 < HH && x1 >= 0 && x1 < WW) ? 1.f : 0.f;
            float m10 = (y1 >= 0 && y1 < HH && x0 >= 0 && x0 < WW) ? 1.f : 0.f;
            float m11 = (y1 >= 0 && y1 < HH && x1 >= 0 && x1 < WW) ? 1.f : 0.f;
            float w00 = (1.f - wy) * (1.f - wx) * m00;
            float w01 = (1.f - wy) * wx * m01;
            float w10 = wy * (1.f - wx) * m10;
            float w11 = wy * wx * m11;
            int cy0 = min(max(y0, 0), HH - 1), cy1 = min(max(y1, 0), HH - 1);
            int cx0 = min(max(x0, 0), WW - 1), cx1 = min(max(x1, 0), WW - 1);
            int a00 = cy0 * WW + cx0, a01 = cy0 * WW + cx1;
            int a10 = cy1 * WW + cx0, a11 = cy1 * WW + cx1;
            const float* ib = ibase + (size_t)(g * 8) * HWP;
#pragma unroll
            for (int cg = 0; cg < 8; ++cg) {
                const float* ip = ib + (size_t)cg * HWP;
                float s = ip[a00] * w00;
                s = fmaf(ip[a01], w01, s);
                s = fmaf(ip[a10], w10, s);
                s = fmaf(ip[a11], w11, s);
                samp[pp * 73 + cg * 9 + kk] = s;
            }
        }
        __syncthreads();
#pragma unroll
        for (int cg = 0; cg < 8; ++cg) {
            int cin = g * 8 + cg;
            const float* wrow = w + ((size_t)(q * 16) * NC + cin) * 9;
#pragma unroll
            for (int kk = 0; kk < 9; ++kk) {
                float s = samp[p * 73 + cg * 9 + kk];
#pragma unroll
                for (int o = 0; o < 16; ++o)
                    acc[o] = fmaf(wrow[(size_t)o * NC * 9 + kk], s, acc[o]);
            }
        }
    }
    const int oy = ty0 + (p >> 3), ox = tx0 + (p & 7);
#pragma unroll
    for (int o = 0; o < 16; ++o) {
        int co = q * 16 + o;
        out[((size_t)jl * NC + co) * HWP + oy * WW + ox] = acc[o];
    }
}

// rec conv (64 -> 3): fp32, tiny. 16x16 tile, 1 px/thread, acc[3]. Writes d_out.
__global__ __launch_bounds__(256) void conv3x3_rec_k(
    const float* __restrict__ in, const float* __restrict__ w,
    const float* __restrict__ bias, float* __restrict__ out, int job0)
{
    constexpr int CB = 8;
    constexpr int PITCH = 48;
    constexpr int CH = 18 * PITCH;
    const int jl = blockIdx.y, jg = job0 + jl;
    const int b = jg & 1, fi = jg >> 1;
    const int frame = fi + (fi >= 2 ? 1 : 0);
    const int tile = blockIdx.x;
    const int ty0 = (tile >> 3) << 4, tx0 = (tile & 7) << 4;
    const int tid = threadIdx.x;
    const int tx = tid & 15, ty = tid >> 4;
    const float* srcA = in + (size_t)jl * NC * HWP;

    __shared__ float lds[CB * CH];
    float acc[3] = {bias[0], bias[1], bias[2]};

    for (int cb = 0; cb < NC; cb += CB) {
        __syncthreads();
        for (int e = tid; e < CB * 324; e += 256) {
            int c = e / 324;
            int r = e - c * 324;
            int iy = r / 18, ix = r - iy * 18;
            int gy = ty0 - 1 + iy, gx = tx0 - 1 + ix;
            const float* s = srcA + (size_t)(cb + c) * HWP;
            float v = 0.f;
            if (gy >= 0 && gy < HH && gx >= 0 && gx < WW) v = s[gy * WW + gx];
            lds[c * CH + iy * PITCH + ix] = v;
        }
        __syncthreads();
#pragma unroll
        for (int c = 0; c < CB; ++c) {
            float t[9];
#pragma unroll
            for (int dy = 0; dy < 3; ++dy)
#pragma unroll
                for (int dx = 0; dx < 3; ++dx)
                    t[dy * 3 + dx] = lds[c * CH + (ty + dy) * PITCH + (tx + dx)];
            int ci = cb + c;
#pragma unroll
            for (int o = 0; o < 3; ++o) {
                const float* wo = w + ((size_t)o * NC + ci) * 9;
#pragma unroll
                for (int kk = 0; kk < 9; ++kk)
                    acc[o] = fmaf(wo[kk], t[kk], acc[o]);
            }
        }
    }
    const int oy = ty0 + ty, ox = tx0 + tx;
#pragma unroll
    for (int o = 0; o < 3; ++o)
        out[((size_t)(b * NN + frame) * 3 + o) * HWP + oy * WW + ox] = acc[o];
}

extern "C" void kernel_launch(void* const* d_in, const int* in_sizes, int n_in,
                              void* d_out, int out_size, void* d_ws, size_t ws_size,
                              hipStream_t stream)
{
    const float* pf    = (const float*)d_in[0];
    const float* xc    = (const float*)d_in[1];
    const float* cr_w  = (const float*)d_in[2];
    const float* cr_b  = (const float*)d_in[3];
    const float* ow[4] = {(const float*)d_in[4],  (const float*)d_in[8],
                          (const float*)d_in[12], (const float*)d_in[16]};
    const float* ob[4] = {(const float*)d_in[5],  (const float*)d_in[9],
                          (const float*)d_in[13], (const float*)d_in[17]};
    const float* dw[4] = {(const float*)d_in[6],  (const float*)d_in[10],
                          (const float*)d_in[14], (const float*)d_in[18]};
    const float* db[4] = {(const float*)d_in[7],  (const float*)d_in[11],
                          (const float*)d_in[15], (const float*)d_in[19]};
    const float* rec_w = (const float*)d_in[20];
    const float* rec_b = (const float*)d_in[21];
    float* out = (float*)d_out;

    // ws layout: [wp split-fp16 weights][A][Bb][O]
    const size_t WPC = (size_t)4 * NKC * 1024;   // 73728 fp16 elems per 4-ct pass
    const size_t WPO = (size_t)9 * NKC * 1024;   // 165888 fp16 elems per 9-ct pass
    _Float16* wp_cr0 = (_Float16*)d_ws;
    _Float16* wp_cr1 = wp_cr0 + WPC;
    _Float16* wp_of[4];
    _Float16* cur = wp_cr1 + WPC;
    for (int i = 0; i < 4; ++i) { wp_of[i] = cur; cur += WPO; }
    size_t wp_bytes = (size_t)((char*)cur - (char*)d_ws);

    const size_t per_job = (size_t)(NC + NC + OFFC) * HWP * sizeof(float);
    int JC = 8;
    while (JC > 1 && wp_bytes + per_job * (size_t)JC > ws_size) JC >>= 1;
    float* A  = (float*)cur;
    float* Bb = A  + (size_t)JC * NC * HWP;
    float* O  = Bb + (size_t)JC * NC * HWP;

    // ---- weight preprocessing (every call; ws is re-poisoned) ----
    {
        int nc4 = 4 * NKC * 64, nc9 = 9 * NKC * 64;
        dim3 b4((nc4 + 255) / 256), b9((nc9 + 255) / 256);
        prew_k<<<b4, 256, 0, stream>>>(cr_w, wp_cr0, 4, 0, 128);
        prew_k<<<b4, 256, 0, stream>>>(cr_w, wp_cr1, 4, 64, 128);
        for (int i = 0; i < 4; ++i)
            prew_k<<<b9, 256, 0, stream>>>(ow[i], wp_of[i], 9, 0, 64);
    }

    copy_center_k<<<dim3((NB * 3 * HWP + 255) / 256), 256, 0, stream>>>(xc, out);

    for (int job0 = 0; job0 < 8; job0 += JC) {
        dim3 blk(256);
        dim3 gconv(128, JC), gdef(256, JC), grec(64, JC);
        // fea1 = cr_conv(concat(ref, supp)) : two K=576 passes (ref, then supp ADD)
        mconv_k<4, 1, 0><<<gconv, blk, 0, stream>>>(nullptr, pf, wp_cr0, cr_b, A, job0);
        mconv_k<4, 2, 1><<<gconv, blk, 0, stream>>>(nullptr, pf, wp_cr1, cr_b, A, job0);
        // off1(fea1); fea2 = deform(fea1)
        mconv_k<9, 0, 0><<<gconv, blk, 0, stream>>>(A, pf, wp_of[0], ob[0], O, job0);
        deform_k<<<gdef, blk, 0, stream>>>(A, O, dw[0], db[0], Bb, job0, 0, pf);
        // off2(fea2); fea3 = deform(fea2)
        mconv_k<9, 0, 0><<<gconv, blk, 0, stream>>>(Bb, pf, wp_of[1], ob[1], O, job0);
        deform_k<<<gdef, blk, 0, stream>>>(Bb, O, dw[1], db[1], A, job0, 0, pf);
        // off3(fea3); fea4 = deform(supp)
        mconv_k<9, 0, 0><<<gconv, blk, 0, stream>>>(A, pf, wp_of[2], ob[2], O, job0);
        deform_k<<<gdef, blk, 0, stream>>>(nullptr, O, dw[2], db[2], Bb, job0, 1, pf);
        // off4(fea4); aligned = deform(fea4)
        mconv_k<9, 0, 0><<<gconv, blk, 0, stream>>>(Bb, pf, wp_of[3], ob[3], O, job0);
        deform_k<<<gdef, blk, 0, stream>>>(Bb, O, dw[3], db[3], A, job0, 0, pf);
        // out[b, frame] = rec_conv(aligned)
        conv3x3_rec_k<<<grec, blk, 0, stream>>>(A, rec_w, rec_b, out, job0);
    }
}